// Round 21
// baseline (35.470 us; speedup 1.0000x reference)
//
#include <hip/hip_runtime.h>
#include <hip/hip_bf16.h>
#include <math.h>

typedef short bf4 __attribute__((ext_vector_type(4)));
typedef float f32x4 __attribute__((ext_vector_type(4)));

constexpr int CC  = 128;
constexpr int NH  = 8;
constexpr int KD  = 16;
constexpr int BB  = 8;
constexpr int NN  = 1024;
constexpr int BHW = BB * NN;
constexpr float LOG2E = 1.44269504088896340736f;
constexpr float MBOUND = 32.0f;   // constant softmax shift (exact rescale)

static __device__ __forceinline__ short f2bf(float x) {
    __hip_bfloat16 b = __float2bfloat16(x);
    short s;
    __builtin_memcpy(&s, &b, 2);
    return s;
}
static __device__ __forceinline__ unsigned fbits(float x) {
    unsigned u;
    __builtin_memcpy(&u, &x, 4);
    return u;
}
static __device__ __forceinline__ float fexp2(float x) {
#if __has_builtin(__builtin_amdgcn_exp2f)
    return __builtin_amdgcn_exp2f(x);
#else
    return exp2f(x);
#endif
}

static __device__ __forceinline__ f32x4 mfma16(bf4 a, bf4 b, f32x4 c) {
#if __has_builtin(__builtin_amdgcn_mfma_f32_16x16x16bf16_1k)
    return __builtin_amdgcn_mfma_f32_16x16x16bf16_1k(a, b, c, 0, 0, 0);
#else
    f32x4 d;
    asm volatile("v_mfma_f32_16x16x16_bf16 %0, %1, %2, %3"
                 : "=&v"(d) : "v"(a), "v"(b), "v"(c));
    return d;
#endif
}

// ---------------- K1: BN partial stats (8-way split) + W->bf16 frags ----
__global__ __launch_bounds__(256) void k_prep(const float* __restrict__ x,
                                              const float* __restrict__ wq,
                                              const float* __restrict__ wk,
                                              const float* __restrict__ wv,
                                              float* __restrict__ ps,
                                              short* __restrict__ wf) {
    int t = threadIdx.x;
    int blk = blockIdx.x;
    if (blk < 1024) {
        int c = blk >> 3, b = blk & 7;
        float4 v = ((const float4*)(x + ((size_t)b * CC + c) * NN))[t];
        float s1 = v.x + v.y + v.z + v.w;
        float s2 = v.x * v.x + v.y * v.y + v.z * v.z + v.w * v.w;
        #pragma unroll
        for (int off = 32; off >= 1; off >>= 1) {
            s1 += __shfl_xor(s1, off);
            s2 += __shfl_xor(s2, off);
        }
        __shared__ float r1[4], r2[4];
        int wid = t >> 6, lane = t & 63;
        if (lane == 0) { r1[wid] = s1; r2[wid] = s2; }
        __syncthreads();
        if (t == 0) {
            ps[(c * 8 + b) * 2 + 0] = r1[0] + r1[1] + r1[2] + r1[3];
            ps[(c * 8 + b) * 2 + 1] = r2[0] + r2[1] + r2[2] + r2[3];
        }
    } else {
        // Wf[((p*8+mt)*8+ct)*64 + ln][jj] = W_p[mt*16+li][ct*16+4*hl+jj]
        int s = (blk - 1024) * 256 + t;   // 0..12287
        int ln = s & 63, ct = (s >> 6) & 7, mt = (s >> 9) & 7, p = s >> 12;
        int hl = ln >> 4, li = ln & 15;
        const float* w = (p == 0) ? wq : (p == 1) ? wk : wv;
        float4 v = *(const float4*)(w + (size_t)(mt * 16 + li) * CC + ct * 16 + 4 * hl);
        float sc = (p == 0) ? 0.25f * LOG2E : 1.0f;
        bf4 r;
        r[0] = f2bf(v.x * sc); r[1] = f2bf(v.y * sc);
        r[2] = f2bf(v.z * sc); r[3] = f2bf(v.w * sc);
        *(bf4*)&wf[(size_t)s * 4] = r;
    }
}

// ---------------- K2: fused BN+GELU + QKV projection via MFMA -----------
// qf/kf/vf stored non-temporally (lands in L3, avoids cross-XCD dirty-L2).
__global__ __launch_bounds__(512) void k_proj(const float* __restrict__ x,
                                              const float* __restrict__ ps,
                                              const float* __restrict__ gamma,
                                              const float* __restrict__ beta,
                                              const short* __restrict__ wf,
                                              short* __restrict__ qf,
                                              short* __restrict__ kf,
                                              short* __restrict__ vf) {
    __shared__ float xS[128][20];     // x tile; reused as per-wave vScr later
    __shared__ float ssS[256];
    __shared__ short afS[8][256];
    int it = blockIdx.x, b = blockIdx.y;
    int t = threadIdx.x;
    if (t < 128) {
        int c = t;
        const float4* pp = (const float4*)(ps + c * 16);
        float4 a0 = pp[0], a1 = pp[1], a2 = pp[2], a3 = pp[3];
        float s1 = a0.x + a0.z + a1.x + a1.z + a2.x + a2.z + a3.x + a3.z;
        float s2 = a0.y + a0.w + a1.y + a1.w + a2.y + a2.w + a3.y + a3.w;
        float mean = s1 / (float)BHW;
        float var  = s2 / (float)BHW - mean * mean;
        float rstd = rsqrtf(var + 1e-5f);
        float sc = rstd * gamma[c];
        ssS[c]       = sc;
        ssS[128 + c] = beta[c] - mean * sc;
    }
    const float* xb = x + (size_t)b * CC * NN + it * 16;
    {
        int r = t >> 2, cf = t & 3;
        float4 v = *(const float4*)(xb + (size_t)r * NN + cf * 4);
        *(float4*)&xS[r][cf * 4] = v;
    }
    __syncthreads();
    {
        int ct = t >> 6, ln = t & 63;
        int hl_ = ln >> 4, li_ = ln & 15;
        int c0 = ct * 16 + 4 * hl_;
        bf4 r;
        #pragma unroll
        for (int jj = 0; jj < 4; ++jj) {
            int c = c0 + jj;
            float v = xS[c][li_] * ssS[c] + ssS[128 + c];
            v = 0.5f * v * (1.0f + erff(v * 0.70710678f));
            r[jj] = f2bf(v);
        }
        *(bf4*)&afS[ct][ln * 4] = r;
    }
    __syncthreads();

    int wid = t >> 6, lane = t & 63;
    int hl = lane >> 4, li = lane & 15;
    f32x4 acc[3];
    #pragma unroll
    for (int e = 0; e < 3; ++e) acc[e] = (f32x4)0.f;
    #pragma unroll
    for (int ct = 0; ct < 8; ++ct) {
        bf4 af = *(const bf4*)&afS[ct][lane * 4];
        #pragma unroll
        for (int e = 0; e < 3; ++e) {
            int mtp = wid + 8 * e;           // p = e, mt = wid
            bf4 wfr = *(const bf4*)(wf + ((size_t)(mtp * 8 + ct) * 64 + lane) * 4);
            acc[e] = mfma16(wfr, af, acc[e]);
        }
    }
    int bq = b * 8;
    #pragma unroll
    for (int e = 0; e < 2; ++e) {
        short* dst = (e == 0) ? qf : kf;
        bf4 r;
        #pragma unroll
        for (int jr = 0; jr < 4; ++jr) r[jr] = f2bf(acc[e][jr]);
        __builtin_nontemporal_store(r,
            (bf4*)&dst[(((size_t)(bq + wid) * 64 + it) * 64 + lane) * 4]);
    }
    // v epilogue: wave-private 16x16 transpose through LDS (lgkmcnt-ordered)
    {
        float* vScrW = &xS[0][0] + wid * 272;   // [16][17] per wave
        #pragma unroll
        for (int r = 0; r < 4; ++r)
            vScrW[(4 * hl + r) * 17 + li] = acc[2][r];
        bf4 r;
        #pragma unroll
        for (int jj = 0; jj < 4; ++jj)
            r[jj] = f2bf(vScrW[li * 17 + 4 * hl + jj]);
        __builtin_nontemporal_store(r,
            (bf4*)&vf[(((size_t)(bq + wid) * 64 + it) * 64 + lane) * 4]);
    }
}

// ---------------- K3: attention, 3-stage software pipeline --------------
// grid (64, 8), block 512. Per chunk: QK(ch+2) || PV(ch) || exp2+pack(ch+1)
// so every dependent VALU block has >=4 independent MFMAs ahead of it and
// every PV is >=8 MFMAs past its pack. Monolithic staging + one barrier.
__global__ __launch_bounds__(512, 4) void k_attn(const short* __restrict__ qf,
                                                 const short* __restrict__ kf,
                                                 const short* __restrict__ vf,
                                                 const float* __restrict__ x,
                                                 const float* __restrict__ peh,
                                                 const float* __restrict__ pew,
                                                 float* __restrict__ out) {
    __shared__ short ldsK[16384];   // 32 KB
    __shared__ short ldsV[16384];   // 32 KB
    __shared__ float phS[64], pwS[64];
    int t = threadIdx.x;
    int bh = blockIdx.x;
    const short* qfh = qf + (size_t)bh * 16384;
    const short* kfh = kf + (size_t)bh * 16384;
    const short* vfh = vf + (size_t)bh * 16384;

    #pragma unroll
    for (int k = 0; k < 4; ++k)
        ((int4*)ldsK)[t + 512 * k] = ((const int4*)kfh)[t + 512 * k];
    #pragma unroll
    for (int k = 0; k < 4; ++k)
        ((int4*)ldsV)[t + 512 * k] = ((const int4*)vfh)[t + 512 * k];
    if (t < 64) {
        phS[t] = (t < 63) ? peh[t] * LOG2E : -1e30f;
        pwS[t] = (t < 63) ? pew[t] * LOG2E : -1e30f;
    }
    __syncthreads();

    int wid = t >> 6, lane = t & 63;
    int li = lane & 15, hl = lane >> 4;
    int it = blockIdx.y * 8 + wid;

    bf4 qfr = *(const bf4*)(qfh + ((size_t)it * 64 + lane) * 4);

    int wi = ((it & 1) << 4) | li;
    float pwm[2][4];
    #pragma unroll
    for (int jp = 0; jp < 2; ++jp)
        #pragma unroll
        for (int r = 0; r < 4; ++r)
            pwm[jp][r] = pwS[wi + 31 - ((jp << 4) + 4 * hl + r)] - MBOUND;

    int hq = it >> 1;
    const float* phBase = &phS[hq];       // chunk offsets become immediates
    const short* kBase = &ldsK[lane * 4]; // + (ch*4+jt)*512B immediate
    const short* vBase = &ldsV[lane * 4];

    f32x4 oaccA = (f32x4)0.f, oaccB = (f32x4)0.f;
    f32x4 lacc0 = (f32x4)0.f, lacc1 = (f32x4)0.f;
    short oneb = (short)0x3F80;           // bf16 1.0
    bf4 ones = {oneb, oneb, oneb, oneb};

    auto qk = [&](int ch, f32x4* s) {
        float ph0 = phBase[31 - 2 * ch];
        float ph1 = phBase[30 - 2 * ch];
        #pragma unroll
        for (int jt = 0; jt < 4; ++jt) {
            bf4 kb = *(const bf4*)(kBase + (ch * 4 + jt) * 256);
            float ph = (jt < 2) ? ph0 : ph1;
            f32x4 c;
            #pragma unroll
            for (int r = 0; r < 4; ++r) c[r] = pwm[jt & 1][r] + ph;
            s[jt] = mfma16(kb, qfr, c);
        }
    };
    // exp2 + truncate-pack s into pf; load V fragments for chunk ch
    auto stage = [&](f32x4* s, bf4* pf, bf4* vb, int ch) {
        #pragma unroll
        for (int jt = 0; jt < 4; ++jt)
            vb[jt] = *(const bf4*)(vBase + (ch * 4 + jt) * 256);
        #pragma unroll
        for (int jt = 0; jt < 4; ++jt)
            #pragma unroll
            for (int r = 0; r < 4; ++r)
                s[jt][r] = fexp2(s[jt][r]);
        #pragma unroll
        for (int jt = 0; jt < 4; ++jt) {
            unsigned lo = __builtin_amdgcn_perm(fbits(s[jt][1]), fbits(s[jt][0]), 0x07060302u);
            unsigned hi = __builtin_amdgcn_perm(fbits(s[jt][3]), fbits(s[jt][2]), 0x07060302u);
            unsigned pk[2] = {lo, hi};
            __builtin_memcpy(&pf[jt], pk, 8);
        }
    };
    auto pv = [&](bf4* vb, bf4* pf) {
        __builtin_amdgcn_s_setprio(1);
        oaccA = mfma16(vb[0], pf[0], oaccA);
        oaccB = mfma16(vb[2], pf[2], oaccB);
        lacc0 = mfma16(ones,  pf[0], lacc0);
        lacc1 = mfma16(ones,  pf[2], lacc1);
        oaccA = mfma16(vb[1], pf[1], oaccA);
        oaccB = mfma16(vb[3], pf[3], oaccB);
        lacc0 = mfma16(ones,  pf[1], lacc0);
        lacc1 = mfma16(ones,  pf[3], lacc1);
        __builtin_amdgcn_s_setprio(0);
    };

    // 3-stage pipeline over 16 chunks, A/B register sets, fully static
    f32x4 sA[4], sB[4];
    bf4 pfA[4], pfB[4], vbA[4], vbB[4];
    qk(0, sA);
    stage(sA, pfA, vbA, 0);
    qk(1, sB);
    #pragma unroll
    for (int h2 = 0; h2 < 8; ++h2) {
        int ch = 2 * h2;
        if (ch + 2 < 16) qk(ch + 2, sA);      // sA free (packed last iter)
        pv(vbA, pfA);                          // PV(ch): pack was >=1 chunk ago
        if (ch + 1 < 16) stage(sB, pfB, vbB, ch + 1);
        if (ch + 3 < 16) qk(ch + 3, sB);
        pv(vbB, pfB);                          // PV(ch+1)
        if (ch + 2 < 16) stage(sA, pfA, vbA, ch + 2);
    }

    // every lane/reg already holds the full sum for its query li
    float rl = 1.0f / (lacc0[0] + lacc1[0]);

    int b = bh >> 3, h = bh & 7;
    size_t base = (size_t)b * (CC * NN) + (size_t)h * KD * NN;
    int i = it * 16 + li;
    #pragma unroll
    for (int r = 0; r < 4; ++r) {
        int d = 4 * hl + r;
        size_t g = base + (size_t)d * NN + i;
        out[g] = x[g] + (oaccA[r] + oaccB[r]) * rl;
    }
}

extern "C" void kernel_launch(void* const* d_in, const int* in_sizes, int n_in,
                              void* d_out, int out_size, void* d_ws, size_t ws_size,
                              hipStream_t stream) {
    const float* x     = (const float*)d_in[0];
    const float* gamma = (const float*)d_in[1];
    const float* beta  = (const float*)d_in[2];
    const float* wq    = (const float*)d_in[3];
    const float* wk    = (const float*)d_in[4];
    const float* wv    = (const float*)d_in[5];
    const float* peh   = (const float*)d_in[6];
    const float* pew   = (const float*)d_in[7];
    float* out = (float*)d_out;
    float* ws  = (float*)d_ws;

    float* ps = ws;                          // 2048 f32 partial sums
    short* wf = (short*)(ws + 2048);         // 49152 shorts: W bf16 frags
    short* qf = wf + 49152;                  // 1M shorts each (2 MB)
    short* kf = qf + (1 << 20);
    short* vf = kf + (1 << 20);

    k_prep<<<1072, 256, 0, stream>>>(x, wq, wk, wv, ps, wf);
    k_proj<<<dim3(64, 8), 512, 0, stream>>>(x, ps, gamma, beta, wf, qf, kf, vf);
    k_attn<<<dim3(64, 8), 512, 0, stream>>>(qf, kf, vf, x, peh, pew, out);
}

// Round 22
// 32.177 us; speedup vs baseline: 1.1023x; 1.1023x over previous
//
#include <hip/hip_runtime.h>
#include <hip/hip_bf16.h>
#include <math.h>

typedef short bf4 __attribute__((ext_vector_type(4)));
typedef float f32x4 __attribute__((ext_vector_type(4)));

constexpr int CC  = 128;
constexpr int NH  = 8;
constexpr int KD  = 16;
constexpr int BB  = 8;
constexpr int NN  = 1024;
constexpr int BHW = BB * NN;
constexpr float LOG2E = 1.44269504088896340736f;
constexpr float MBOUND = 32.0f;   // constant softmax shift (exact rescale)

static __device__ __forceinline__ short f2bf(float x) {
    __hip_bfloat16 b = __float2bfloat16(x);
    short s;
    __builtin_memcpy(&s, &b, 2);
    return s;
}
static __device__ __forceinline__ unsigned fbits(float x) {
    unsigned u;
    __builtin_memcpy(&u, &x, 4);
    return u;
}
static __device__ __forceinline__ float fexp2(float x) {
#if __has_builtin(__builtin_amdgcn_exp2f)
    return __builtin_amdgcn_exp2f(x);
#else
    return exp2f(x);
#endif
}

static __device__ __forceinline__ f32x4 mfma16(bf4 a, bf4 b, f32x4 c) {
#if __has_builtin(__builtin_amdgcn_mfma_f32_16x16x16bf16_1k)
    return __builtin_amdgcn_mfma_f32_16x16x16bf16_1k(a, b, c, 0, 0, 0);
#else
    f32x4 d;
    asm volatile("v_mfma_f32_16x16x16_bf16 %0, %1, %2, %3"
                 : "=&v"(d) : "v"(a), "v"(b), "v"(c));
    return d;
#endif
}

// ---------------- K1: BN partial stats (8-way split) + W->bf16 frags ----
__global__ __launch_bounds__(256) void k_prep(const float* __restrict__ x,
                                              const float* __restrict__ wq,
                                              const float* __restrict__ wk,
                                              const float* __restrict__ wv,
                                              float* __restrict__ ps,
                                              short* __restrict__ wf) {
    int t = threadIdx.x;
    int blk = blockIdx.x;
    if (blk < 1024) {
        int c = blk >> 3, b = blk & 7;
        float4 v = ((const float4*)(x + ((size_t)b * CC + c) * NN))[t];
        float s1 = v.x + v.y + v.z + v.w;
        float s2 = v.x * v.x + v.y * v.y + v.z * v.z + v.w * v.w;
        #pragma unroll
        for (int off = 32; off >= 1; off >>= 1) {
            s1 += __shfl_xor(s1, off);
            s2 += __shfl_xor(s2, off);
        }
        __shared__ float r1[4], r2[4];
        int wid = t >> 6, lane = t & 63;
        if (lane == 0) { r1[wid] = s1; r2[wid] = s2; }
        __syncthreads();
        if (t == 0) {
            ps[(c * 8 + b) * 2 + 0] = r1[0] + r1[1] + r1[2] + r1[3];
            ps[(c * 8 + b) * 2 + 1] = r2[0] + r2[1] + r2[2] + r2[3];
        }
    } else {
        // Wf[((p*8+mt)*8+ct)*64 + ln][jj] = W_p[mt*16+li][ct*16+4*hl+jj]
        int s = (blk - 1024) * 256 + t;   // 0..12287
        int ln = s & 63, ct = (s >> 6) & 7, mt = (s >> 9) & 7, p = s >> 12;
        int hl = ln >> 4, li = ln & 15;
        const float* w = (p == 0) ? wq : (p == 1) ? wk : wv;
        float4 v = *(const float4*)(w + (size_t)(mt * 16 + li) * CC + ct * 16 + 4 * hl);
        float sc = (p == 0) ? 0.25f * LOG2E : 1.0f;
        bf4 r;
        r[0] = f2bf(v.x * sc); r[1] = f2bf(v.y * sc);
        r[2] = f2bf(v.z * sc); r[3] = f2bf(v.w * sc);
        *(bf4*)&wf[(size_t)s * 4] = r;
    }
}

// ---------------- K2: fused BN+GELU + QKV projection via MFMA -----------
// qf/kf/vf stored non-temporally (lands in L3, avoids cross-XCD dirty-L2).
__global__ __launch_bounds__(512) void k_proj(const float* __restrict__ x,
                                              const float* __restrict__ ps,
                                              const float* __restrict__ gamma,
                                              const float* __restrict__ beta,
                                              const short* __restrict__ wf,
                                              short* __restrict__ qf,
                                              short* __restrict__ kf,
                                              short* __restrict__ vf) {
    __shared__ float xS[128][20];     // x tile; reused as per-wave vScr later
    __shared__ float ssS[256];
    __shared__ short afS[8][256];
    int it = blockIdx.x, b = blockIdx.y;
    int t = threadIdx.x;
    if (t < 128) {
        int c = t;
        const float4* pp = (const float4*)(ps + c * 16);
        float4 a0 = pp[0], a1 = pp[1], a2 = pp[2], a3 = pp[3];
        float s1 = a0.x + a0.z + a1.x + a1.z + a2.x + a2.z + a3.x + a3.z;
        float s2 = a0.y + a0.w + a1.y + a1.w + a2.y + a2.w + a3.y + a3.w;
        float mean = s1 / (float)BHW;
        float var  = s2 / (float)BHW - mean * mean;
        float rstd = rsqrtf(var + 1e-5f);
        float sc = rstd * gamma[c];
        ssS[c]       = sc;
        ssS[128 + c] = beta[c] - mean * sc;
    }
    const float* xb = x + (size_t)b * CC * NN + it * 16;
    {
        int r = t >> 2, cf = t & 3;
        float4 v = *(const float4*)(xb + (size_t)r * NN + cf * 4);
        *(float4*)&xS[r][cf * 4] = v;
    }
    __syncthreads();
    {
        int ct = t >> 6, ln = t & 63;
        int hl_ = ln >> 4, li_ = ln & 15;
        int c0 = ct * 16 + 4 * hl_;
        bf4 r;
        #pragma unroll
        for (int jj = 0; jj < 4; ++jj) {
            int c = c0 + jj;
            float v = xS[c][li_] * ssS[c] + ssS[128 + c];
            v = 0.5f * v * (1.0f + erff(v * 0.70710678f));
            r[jj] = f2bf(v);
        }
        *(bf4*)&afS[ct][ln * 4] = r;
    }
    __syncthreads();

    int wid = t >> 6, lane = t & 63;
    int hl = lane >> 4, li = lane & 15;
    f32x4 acc[3];
    #pragma unroll
    for (int e = 0; e < 3; ++e) acc[e] = (f32x4)0.f;
    #pragma unroll
    for (int ct = 0; ct < 8; ++ct) {
        bf4 af = *(const bf4*)&afS[ct][lane * 4];
        #pragma unroll
        for (int e = 0; e < 3; ++e) {
            int mtp = wid + 8 * e;           // p = e, mt = wid
            bf4 wfr = *(const bf4*)(wf + ((size_t)(mtp * 8 + ct) * 64 + lane) * 4);
            acc[e] = mfma16(wfr, af, acc[e]);
        }
    }
    int bq = b * 8;
    #pragma unroll
    for (int e = 0; e < 2; ++e) {
        short* dst = (e == 0) ? qf : kf;
        bf4 r;
        #pragma unroll
        for (int jr = 0; jr < 4; ++jr) r[jr] = f2bf(acc[e][jr]);
        __builtin_nontemporal_store(r,
            (bf4*)&dst[(((size_t)(bq + wid) * 64 + it) * 64 + lane) * 4]);
    }
    // v epilogue: wave-private 16x16 transpose through LDS (lgkmcnt-ordered)
    {
        float* vScrW = &xS[0][0] + wid * 272;   // [16][17] per wave
        #pragma unroll
        for (int r = 0; r < 4; ++r)
            vScrW[(4 * hl + r) * 17 + li] = acc[2][r];
        bf4 r;
        #pragma unroll
        for (int jj = 0; jj < 4; ++jj)
            r[jj] = f2bf(vScrW[li * 17 + 4 * hl + jj]);
        __builtin_nontemporal_store(r,
            (bf4*)&vf[(((size_t)(bq + wid) * 64 + it) * 64 + lane) * 4]);
    }
}

// ---------------- K3: attention, 4-phase pipelined staging --------------
__global__ __launch_bounds__(512, 4) void k_attn(const short* __restrict__ qf,
                                                 const short* __restrict__ kf,
                                                 const short* __restrict__ vf,
                                                 const float* __restrict__ x,
                                                 const float* __restrict__ peh,
                                                 const float* __restrict__ pew,
                                                 float* __restrict__ out) {
    __shared__ short ldsK[16384];   // 32 KB
    __shared__ short ldsV[16384];   // 32 KB
    __shared__ float phS[64], pwS[64];
    int t = threadIdx.x;
    int bh = blockIdx.x;
    const short* qfh = qf + (size_t)bh * 16384;
    const short* kfh = kf + (size_t)bh * 16384;
    const short* vfh = vf + (size_t)bh * 16384;

    // issue ALL staging loads; they stay in flight until their phase write
    int4 kreg[4], vreg[4];
    #pragma unroll
    for (int k = 0; k < 4; ++k) kreg[k] = ((const int4*)kfh)[t + 512 * k];
    #pragma unroll
    for (int k = 0; k < 4; ++k) vreg[k] = ((const int4*)vfh)[t + 512 * k];
    if (t < 64) {
        phS[t] = (t < 63) ? peh[t] * LOG2E : -1e30f;
        pwS[t] = (t < 63) ? pew[t] * LOG2E : -1e30f;
    }

    int wid = t >> 6, lane = t & 63;
    int li = lane & 15, hl = lane >> 4;
    int it = blockIdx.y * 8 + wid;
    bf4 qfr = *(const bf4*)(qfh + ((size_t)it * 64 + lane) * 4);

    // phase-0 write + barrier (lgkmcnt only; vmem loads stay outstanding)
    ((int4*)ldsK)[t] = kreg[0];
    ((int4*)ldsV)[t] = vreg[0];
    asm volatile("s_waitcnt lgkmcnt(0)" ::: "memory");
    __builtin_amdgcn_s_barrier();

    int wi = ((it & 1) << 4) | li;
    float pwm[2][4];
    #pragma unroll
    for (int jp = 0; jp < 2; ++jp)
        #pragma unroll
        for (int r = 0; r < 4; ++r)
            pwm[jp][r] = pwS[wi + 31 - ((jp << 4) + 4 * hl + r)] - MBOUND;

    int hq = it >> 1;
    const float* phBase = &phS[hq];
    const short* kBase = &ldsK[lane * 4];
    const short* vBase = &ldsV[lane * 4];

    f32x4 oaccA = (f32x4)0.f, oaccB = (f32x4)0.f;
    f32x4 lacc0 = (f32x4)0.f, lacc1 = (f32x4)0.f;
    short oneb = (short)0x3F80;           // bf16 1.0
    bf4 ones = {oneb, oneb, oneb, oneb};

    auto qk = [&](int ch, f32x4* s) {
        float ph0 = phBase[31 - 2 * ch];
        float ph1 = phBase[30 - 2 * ch];
        #pragma unroll
        for (int jt = 0; jt < 4; ++jt) {
            bf4 kb = *(const bf4*)(kBase + (ch * 4 + jt) * 256);
            float ph = (jt < 2) ? ph0 : ph1;
            f32x4 c;
            #pragma unroll
            for (int r = 0; r < 4; ++r) c[r] = pwm[jt & 1][r] + ph;
            s[jt] = mfma16(kb, qfr, c);
        }
    };
    auto body = [&](f32x4* s_cur, int ch) {
        bf4 vb[4];
        #pragma unroll
        for (int jt = 0; jt < 4; ++jt)
            vb[jt] = *(const bf4*)(vBase + (ch * 4 + jt) * 256);
        #pragma unroll
        for (int jt = 0; jt < 4; ++jt)
            #pragma unroll
            for (int r = 0; r < 4; ++r)
                s_cur[jt][r] = fexp2(s_cur[jt][r]);
        bf4 pf[4];
        #pragma unroll
        for (int jt = 0; jt < 4; ++jt) {
            unsigned lo = __builtin_amdgcn_perm(fbits(s_cur[jt][1]), fbits(s_cur[jt][0]), 0x07060302u);
            unsigned hi = __builtin_amdgcn_perm(fbits(s_cur[jt][3]), fbits(s_cur[jt][2]), 0x07060302u);
            unsigned pk[2] = {lo, hi};
            __builtin_memcpy(&pf[jt], pk, 8);
        }
        __builtin_amdgcn_s_setprio(1);
        oaccA = mfma16(vb[0], pf[0], oaccA);
        oaccB = mfma16(vb[2], pf[2], oaccB);
        lacc0 = mfma16(ones,  pf[0], lacc0);
        lacc1 = mfma16(ones,  pf[2], lacc1);
        oaccA = mfma16(vb[1], pf[1], oaccA);
        oaccB = mfma16(vb[3], pf[3], oaccB);
        lacc0 = mfma16(ones,  pf[1], lacc0);
        lacc1 = mfma16(ones,  pf[3], lacc1);
        __builtin_amdgcn_s_setprio(0);
    };

    f32x4 s_cur[4];
    qk(0, s_cur);
    #pragma unroll
    for (int p = 0; p < 4; ++p) {
        // overlap next quarter's LDS write with this phase's compute
        if (p < 3) {
            ((int4*)ldsK)[t + 512 * (p + 1)] = kreg[p + 1];
            ((int4*)ldsV)[t + 512 * (p + 1)] = vreg[p + 1];
        }
        #pragma unroll
        for (int c = 0; c < 4; ++c) {
            int ch = 4 * p + c;
            f32x4 s_nxt[4];
            if (c < 3) qk(ch + 1, s_nxt);
            body(s_cur, ch);
            if (c < 3) {
                #pragma unroll
                for (int jt = 0; jt < 4; ++jt) s_cur[jt] = s_nxt[jt];
            }
        }
        if (p < 3) {
            asm volatile("s_waitcnt lgkmcnt(0)" ::: "memory");
            __builtin_amdgcn_s_barrier();
            qk(4 * (p + 1), s_cur);
        }
    }

    // every lane/reg already holds the full sum for its query li
    float rl = 1.0f / (lacc0[0] + lacc1[0]);

    int b = bh >> 3, h = bh & 7;
    size_t base = (size_t)b * (CC * NN) + (size_t)h * KD * NN;
    int i = it * 16 + li;
    #pragma unroll
    for (int r = 0; r < 4; ++r) {
        int d = 4 * hl + r;
        size_t g = base + (size_t)d * NN + i;
        out[g] = x[g] + (oaccA[r] + oaccB[r]) * rl;
    }
}

extern "C" void kernel_launch(void* const* d_in, const int* in_sizes, int n_in,
                              void* d_out, int out_size, void* d_ws, size_t ws_size,
                              hipStream_t stream) {
    const float* x     = (const float*)d_in[0];
    const float* gamma = (const float*)d_in[1];
    const float* beta  = (const float*)d_in[2];
    const float* wq    = (const float*)d_in[3];
    const float* wk    = (const float*)d_in[4];
    const float* wv    = (const float*)d_in[5];
    const float* peh   = (const float*)d_in[6];
    const float* pew   = (const float*)d_in[7];
    float* out = (float*)d_out;
    float* ws  = (float*)d_ws;

    float* ps = ws;                          // 2048 f32 partial sums
    short* wf = (short*)(ws + 2048);         // 49152 shorts: W bf16 frags
    short* qf = wf + 49152;                  // 1M shorts each (2 MB)
    short* kf = qf + (1 << 20);
    short* vf = kf + (1 << 20);

    k_prep<<<1072, 256, 0, stream>>>(x, wq, wk, wv, ps, wf);
    k_proj<<<dim3(64, 8), 512, 0, stream>>>(x, ps, gamma, beta, wf, qf, kf, vf);
    k_attn<<<dim3(64, 8), 512, 0, stream>>>(qf, kf, vf, x, peh, pew, out);
}